// Round 18
// baseline (56.648 us; speedup 1.0000x reference)
//
#include <hip/hip_runtime.h>
#include <cstdint>
#include <cstddef>

// ContrastiveLoss: B=8192, D=256 fp32 inputs.
// loss = mean_b [ log( exp(2*pos_b) + sum_c exp(2*z_i[b].z_k[c]) ) - 2*pos_b ]
// R17 == R16 with the compile fix (__exp2f -> exp2f; lowers to v_exp_f32).
// fp8-MX MFMA, LDS-A + global-B, three measured-leak fixes:
//  - split-half frag layout: frag = 2048 B = 2 x 1024 B halves; lane l owns
//    bytes [h*1024 + l*16, +16). LDS reads at stride 16 B/lane
//    (conflict-free per R10); B global reads stay coalesced dwordx4 pairs.
//  - B register ring depth 4, fully unrolled 16-step loop (compile-time
//    offsets; refill distance 4 steps >= L2 latency).
//  - z_i packed with log2(e) folded (x1.4427); scale A = 2.0 (0x80) gives
//    acc = 2*log2e*(z.z) -> epilogue is bare exp2f (v_exp_f32, no mul).
// exp2 fused per col-tile; 32-lane shuffle-reduce + atomics once per block.

constexpr int   D_DIM = 256;
constexpr float INV_T = 2.0f;        // 1/T, T=0.5
constexpr float LOG2E = 1.44269504f;

constexpr int BM = 128;         // block rows
constexpr int NT = 4;           // col-tiles per block (each 128 cols)

typedef __attribute__((ext_vector_type(8)))  int   i32x8;
typedef __attribute__((ext_vector_type(4)))  int   i32x4;
typedef __attribute__((ext_vector_type(16))) float f32x16;

__device__ __forceinline__ void gload_lds16(const void* g, void* l) {
    auto gp = reinterpret_cast<const __attribute__((address_space(1))) unsigned int*>(
        reinterpret_cast<uintptr_t>(g));
    auto lp = reinterpret_cast<__attribute__((address_space(3))) unsigned int*>(
        reinterpret_cast<uintptr_t>(l));
    __builtin_amdgcn_global_load_lds(gp, lp, 16, 0, 0);
}

// ---------------------------------------------------------------------------
// Kernel 1: per-16-row group: norms, pos_logit, rowsum init, PACKED e4m3 out.
// Thread t: row_local = t>>4, chunk c = t&15 (16 elems, k in [c*16,+16)).
// Split-half pack: frag f = (row>>5)*4 + (c>>2);
//   lane = (row&31) + 32*((c>>1)&1); half = c&1;
//   byte = f*2048 + half*1024 + lane*16   -> one aligned 16-byte store.
// z_i additionally scaled by LOG2E (so GEMM's scale-A=2.0 yields exp2 arg).
// ---------------------------------------------------------------------------
__global__ __launch_bounds__(256) void prep_kernel(
    const float* __restrict__ ei, const float* __restrict__ ej,
    const float* __restrict__ ek,
    unsigned char* __restrict__ zip, unsigned char* __restrict__ zkp,
    float* __restrict__ pos_logit, float* __restrict__ rowsum)
{
    const int t  = (int)threadIdx.x;
    const int rl = t >> 4;              // row within group (0..15)
    const int c  = t & 15;              // 16-elem chunk (0..15)
    const int g  = (int)blockIdx.x;     // 16-row group
    const int row = g * 16 + rl;

    const float4* pi = (const float4*)(ei + (size_t)row * D_DIM + c * 16);
    const float4* pj = (const float4*)(ej + (size_t)row * D_DIM + c * 16);
    const float4* pk = (const float4*)(ek + (size_t)row * D_DIM + c * 16);
    float4 vi[4], vj[4], vk[4];
    #pragma unroll
    for (int q = 0; q < 4; ++q) { vi[q] = pi[q]; vj[q] = pj[q]; vk[q] = pk[q]; }

    float ssi = 0.f, ssj = 0.f, ssk = 0.f, dij = 0.f;
    #pragma unroll
    for (int q = 0; q < 4; ++q) {
        ssi += vi[q].x*vi[q].x + vi[q].y*vi[q].y + vi[q].z*vi[q].z + vi[q].w*vi[q].w;
        ssj += vj[q].x*vj[q].x + vj[q].y*vj[q].y + vj[q].z*vj[q].z + vj[q].w*vj[q].w;
        ssk += vk[q].x*vk[q].x + vk[q].y*vk[q].y + vk[q].z*vk[q].z + vk[q].w*vk[q].w;
        dij += vi[q].x*vj[q].x + vi[q].y*vj[q].y + vi[q].z*vj[q].z + vi[q].w*vj[q].w;
    }
    #pragma unroll
    for (int off = 1; off <= 8; off <<= 1) {    // reduce over the 16 c-lanes
        ssi += __shfl_xor(ssi, off);
        ssj += __shfl_xor(ssj, off);
        ssk += __shfl_xor(ssk, off);
        dij += __shfl_xor(dij, off);
    }
    const float rn = 1.0f / fmaxf(sqrtf(ssi), 1e-12f);
    const float ri = rn * LOG2E;                          // fold log2(e)
    const float rj = 1.0f / fmaxf(sqrtf(ssj), 1e-12f);
    const float rk = 1.0f / fmaxf(sqrtf(ssk), 1e-12f);

    uint4 uiv, ukv;
    {
        unsigned int wi[4], wk[4];
        #pragma unroll
        for (int q = 0; q < 4; ++q) {
            const float* fi = &vi[q].x;
            const float* fk = &vk[q].x;
            int a = 0, b = 0;
            a = __builtin_amdgcn_cvt_pk_fp8_f32(fi[0] * ri, fi[1] * ri, a, false);
            a = __builtin_amdgcn_cvt_pk_fp8_f32(fi[2] * ri, fi[3] * ri, a, true);
            b = __builtin_amdgcn_cvt_pk_fp8_f32(fk[0] * rk, fk[1] * rk, b, false);
            b = __builtin_amdgcn_cvt_pk_fp8_f32(fk[2] * rk, fk[3] * rk, b, true);
            wi[q] = (unsigned int)a;
            wk[q] = (unsigned int)b;
        }
        uiv = make_uint4(wi[0], wi[1], wi[2], wi[3]);
        ukv = make_uint4(wk[0], wk[1], wk[2], wk[3]);
    }
    const int f    = (row >> 5) * 4 + (c >> 2);
    const int lane = (row & 31) + 32 * ((c >> 1) & 1);
    const size_t off = (size_t)f * 2048 + (c & 1) * 1024 + lane * 16;
    *(uint4*)(zip + off) = uiv;
    *(uint4*)(zkp + off) = ukv;

    if (c == 0) {
        pos_logit[row] = dij * rn * rj * INV_T;   // plain 2*(zi.zj), no log2e
        rowsum[row]    = 0.0f;
    }
}

// ---------------------------------------------------------------------------
// Kernel 2: rows [by*128,+128) x cols [bx*512,+512) of exp2-sum of
// 2*log2e*(z_i . z_k). 4 waves (2x2): wr=w>>1, wc=w&1; wave tile 64x64 =
// 2x2 frags of 32x32 K=64; 16 K-steps fully unrolled.
// A: 16 frags = 32 KB LDS (linear gload_lds; 16 B/lane reads, conflict-free).
// B: global, register ring depth 4 (refill distance 4 steps ~ 400+ cyc).
// Scale A = 2.0 (0x80, the 1/T); scale B = 1.0 (0x7F).
// ---------------------------------------------------------------------------
__global__ __launch_bounds__(256) void sim_mfma_kernel(
    const unsigned char* __restrict__ zip, const unsigned char* __restrict__ zkp,
    float* __restrict__ rowsum)
{
    __shared__ __attribute__((aligned(16))) unsigned char Alds[16 * 2048];

    const int t  = (int)threadIdx.x;
    const int w  = t >> 6;        // wave 0..3
    const int l  = t & 63;
    const int wr = w >> 1;        // row half (0..1)
    const int wc = w & 1;         // col half (0..1)
    const int rowBase = (int)blockIdx.y * BM;

    // ---- stage A panel: global frags [by*16,+16) contiguous 32 KB.
    const unsigned char* Ap = zip + (size_t)blockIdx.y * 16 * 2048;
    #pragma unroll
    for (int f = 0; f < 4; ++f) {
        const int fi = w * 4 + f;
        gload_lds16(Ap + (size_t)fi * 2048 +        (size_t)l * 16,
                    &Alds[fi * 2048]);
        gload_lds16(Ap + (size_t)fi * 2048 + 1024 + (size_t)l * 16,
                    &Alds[fi * 2048 + 1024]);
    }
    asm volatile("s_waitcnt vmcnt(0)" ::: "memory");
    __builtin_amdgcn_s_barrier();      // the ONLY barrier

    // ---- A frag read (LDS, split-half): local frag (mi,kt)=(wr*2+mi)*4+kt;
    // lane l reads 16 B at +l*16 in each half (conflict-free stride).
    #define LDA(dst, kt_) {                                                   \
        _Pragma("unroll")                                                     \
        for (int mi = 0; mi < 2; ++mi) {                                      \
            const int fb_ = ((wr * 2 + mi) * 4 + (kt_)) * 2048 + l * 16;      \
            i32x4 lo_ = *(const i32x4*)&Alds[fb_];                            \
            i32x4 hi_ = *(const i32x4*)&Alds[fb_ + 1024];                     \
            dst[mi] = (i32x8){lo_[0], lo_[1], lo_[2], lo_[3],                 \
                              hi_[0], hi_[1], hi_[2], hi_[3]};                \
        }                                                                     \
    }
    // ---- B frags (global, split-half): col-group = bx*16 + wc*2 + nt*4 + ni;
    // frag byte base = group*4*2048 + kt*2048; lane offset h*1024 + l*16.
    const unsigned char* Bbase =
        zkp + ((size_t)((int)blockIdx.x * 16 + wc * 2) * 4) * 2048 + (size_t)l * 16;
    #define LDB(dst, s_) {                                                    \
        const int nt_ = (s_) >> 2, kt_ = (s_) & 3;                            \
        _Pragma("unroll")                                                     \
        for (int ni = 0; ni < 2; ++ni) {                                      \
            const size_t fb_ = (size_t)(((nt_ * 4 + ni) * 4 + kt_)) * 2048;   \
            i32x4 lo_ = *(const i32x4*)(Bbase + fb_);                         \
            i32x4 hi_ = *(const i32x4*)(Bbase + fb_ + 1024);                  \
            dst[ni] = (i32x8){lo_[0], lo_[1], lo_[2], lo_[3],                 \
                              hi_[0], hi_[1], hi_[2], hi_[3]};                \
        }                                                                     \
    }

    // ---- B ring, depth 4 (static names; slot = s & 3) ----
    i32x8 b0[2], b1[2], b2[2], b3[2];
    LDB(b0, 0); LDB(b1, 1); LDB(b2, 2); LDB(b3, 3);

    float partAcc[2][16] = {};

    #pragma unroll
    for (int nt = 0; nt < NT; ++nt) {
        f32x16 acc[2][2] = {};

        #pragma unroll
        for (int k4 = 0; k4 < 4; ++k4) {
            const int s  = nt * 4 + k4;           // compile-time (both unrolled)
            const int s4 = (s + 4 > NT * 4 - 1) ? (NT * 4 - 1) : (s + 4);

            i32x8 a[2];
            LDA(a, k4);

            __builtin_amdgcn_s_setprio(1);
            #pragma unroll
            for (int mi = 0; mi < 2; ++mi)
                #pragma unroll
                for (int ni = 0; ni < 2; ++ni)
                    acc[mi][ni] = __builtin_amdgcn_mfma_scale_f32_32x32x64_f8f6f4(
                        a[mi],
                        (s % 4 == 0) ? b0[ni] : (s % 4 == 1) ? b1[ni]
                                     : (s % 4 == 2) ? b2[ni] : b3[ni],
                        acc[mi][ni],
                        0, 0,                 // cbsz=fp8(A), blgp=fp8(B)
                        0, 0x00000080,        // scale A = 2.0 (1/T)
                        0, 0x0000007F);       // scale B = 1.0
            __builtin_amdgcn_s_setprio(0);

            // refill this slot for step s+4 (distance 4)
            if (s % 4 == 0)      { LDB(b0, s4); }
            else if (s % 4 == 1) { LDB(b1, s4); }
            else if (s % 4 == 2) { LDB(b2, s4); }
            else                 { LDB(b3, s4); }
        }

        // per-tile epilogue: bare exp2 + in-lane partial sums
        #pragma unroll
        for (int mi = 0; mi < 2; ++mi)
            #pragma unroll
            for (int r = 0; r < 16; ++r)
                partAcc[mi][r] += exp2f(acc[mi][0][r]) + exp2f(acc[mi][1][r]);
    }
    #undef LDA
    #undef LDB

    // block epilogue: reduce across the 32 column-lanes (xor<32 stays in half)
    #pragma unroll
    for (int off = 1; off <= 16; off <<= 1)
        #pragma unroll
        for (int mi = 0; mi < 2; ++mi)
            #pragma unroll
            for (int r = 0; r < 16; ++r)
                partAcc[mi][r] += __shfl_xor(partAcc[mi][r], off);

    if ((l & 31) == 0) {
        const int hi = l >> 5;           // C/D: row = (r&3) + 8*(r>>2) + 4*hi
        #pragma unroll
        for (int mi = 0; mi < 2; ++mi)
            #pragma unroll
            for (int r = 0; r < 16; ++r) {
                const int rr = (r & 3) + 8 * (r >> 2) + 4 * hi;
                atomicAdd(&rowsum[rowBase + wr * 64 + mi * 32 + rr],
                          partAcc[mi][r]);
            }
    }
}

// ---------------------------------------------------------------------------
// Kernel 3: loss = mean_b [ log(exp(pos_b) + rowsum_b) - pos_b ]
// ---------------------------------------------------------------------------
__global__ __launch_bounds__(1024) void finalize_kernel(
    const float* __restrict__ pos_logit, const float* __restrict__ rowsum,
    float* __restrict__ out, int B)
{
    __shared__ float red[1024];
    float acc = 0.f;
    for (int b = (int)threadIdx.x; b < B; b += 1024) {
        const float pl = pos_logit[b];
        acc += logf(expf(pl) + rowsum[b]) - pl;
    }
    red[threadIdx.x] = acc;
    __syncthreads();
    #pragma unroll
    for (int s = 512; s; s >>= 1) {
        if ((int)threadIdx.x < s) red[threadIdx.x] += red[threadIdx.x + s];
        __syncthreads();
    }
    if (threadIdx.x == 0) out[0] = red[0] / (float)B;
}

// ---------------------------------------------------------------------------
extern "C" void kernel_launch(void* const* d_in, const int* in_sizes, int n_in,
                              void* d_out, int out_size, void* d_ws, size_t ws_size,
                              hipStream_t stream)
{
    const float* ei = (const float*)d_in[0];
    const float* ej = (const float*)d_in[1];
    const float* ek = (const float*)d_in[2];
    const int B = in_sizes[0] / D_DIM;   // 8192

    unsigned char* zip = (unsigned char*)d_ws;              // 2 MB packed fp8
    unsigned char* zkp = zip + (size_t)B * D_DIM;           // 2 MB packed fp8
    float* rowsum      = (float*)(zkp + (size_t)B * D_DIM);
    float* pos_logit   = rowsum + B;

    prep_kernel<<<dim3(B / 16), dim3(256), 0, stream>>>(
        ei, ej, ek, zip, zkp, pos_logit, rowsum);

    dim3 grid(B / (NT * 128), B / BM);   // (16, 64) = 1024 blocks
    sim_mfma_kernel<<<grid, dim3(256), 0, stream>>>(zip, zkp, rowsum);

    finalize_kernel<<<dim3(1), dim3(1024), 0, stream>>>(
        pos_logit, rowsum, (float*)d_out, B);
}

// Round 19
// 47.203 us; speedup vs baseline: 1.2001x; 1.2001x over previous
//
#include <hip/hip_runtime.h>
#include <cstdint>
#include <cstddef>

// ContrastiveLoss: B=8192, D=256 fp32 inputs.
// loss = mean_b [ log( exp(2*pos_b) + sum_c exp(2*z_i[b].z_k[c]) ) - 2*pos_b ]
// R18: occupancy-bin fix. All prior rounds sat at >128 unified regs (VGPR +
// AGPR) -> 8 waves/CU. This round: wave tile 32x32 (acc=16 AGPR), ~95 VGPR
// -> <=128 total -> 16 waves/CU (4/SIMD) for latency hiding.
//   Block: 128 rows x 512 cols; 4 waves = 32-row slices. 64 K-steps
//   (16 col-tiles x 4 kt), 1 MFMA_scale_32x32x64 per step.
//   A: 16 frags (32 KB) in LDS, linear gload_lds, 16 B/lane reads.
//   B: register ring depth 4 (distance-4 refill); all 4 waves load the SAME
//   B frag -> L1 broadcast. No barriers in the loop.
// z_i packed with log2(e) folded; scale A = 2.0 (0x80) = the 1/T.
// exp2 fused per col-tile; lane-reduce + atomics once per wave at the end.

constexpr int   D_DIM = 256;
constexpr float INV_T = 2.0f;        // 1/T, T=0.5
constexpr float LOG2E = 1.44269504f;

constexpr int BM = 128;         // block rows
constexpr int NT = 16;          // col-tiles per block (each 32 cols)

typedef __attribute__((ext_vector_type(8)))  int   i32x8;
typedef __attribute__((ext_vector_type(4)))  int   i32x4;
typedef __attribute__((ext_vector_type(16))) float f32x16;

__device__ __forceinline__ void gload_lds16(const void* g, void* l) {
    auto gp = reinterpret_cast<const __attribute__((address_space(1))) unsigned int*>(
        reinterpret_cast<uintptr_t>(g));
    auto lp = reinterpret_cast<__attribute__((address_space(3))) unsigned int*>(
        reinterpret_cast<uintptr_t>(l));
    __builtin_amdgcn_global_load_lds(gp, lp, 16, 0, 0);
}

// ---------------------------------------------------------------------------
// Kernel 1: per-16-row group: norms, pos_logit, rowsum init, PACKED e4m3 out.
// (unchanged from R17 — verified correct)
// Split-half pack: frag f = (row>>5)*4 + (c>>2);
//   lane = (row&31) + 32*((c>>1)&1); half = c&1;
//   byte = f*2048 + half*1024 + lane*16.
// z_i additionally scaled by LOG2E (so GEMM's scale-A=2.0 yields exp2 arg).
// ---------------------------------------------------------------------------
__global__ __launch_bounds__(256) void prep_kernel(
    const float* __restrict__ ei, const float* __restrict__ ej,
    const float* __restrict__ ek,
    unsigned char* __restrict__ zip, unsigned char* __restrict__ zkp,
    float* __restrict__ pos_logit, float* __restrict__ rowsum)
{
    const int t  = (int)threadIdx.x;
    const int rl = t >> 4;              // row within group (0..15)
    const int c  = t & 15;              // 16-elem chunk (0..15)
    const int g  = (int)blockIdx.x;     // 16-row group
    const int row = g * 16 + rl;

    const float4* pi = (const float4*)(ei + (size_t)row * D_DIM + c * 16);
    const float4* pj = (const float4*)(ej + (size_t)row * D_DIM + c * 16);
    const float4* pk = (const float4*)(ek + (size_t)row * D_DIM + c * 16);
    float4 vi[4], vj[4], vk[4];
    #pragma unroll
    for (int q = 0; q < 4; ++q) { vi[q] = pi[q]; vj[q] = pj[q]; vk[q] = pk[q]; }

    float ssi = 0.f, ssj = 0.f, ssk = 0.f, dij = 0.f;
    #pragma unroll
    for (int q = 0; q < 4; ++q) {
        ssi += vi[q].x*vi[q].x + vi[q].y*vi[q].y + vi[q].z*vi[q].z + vi[q].w*vi[q].w;
        ssj += vj[q].x*vj[q].x + vj[q].y*vj[q].y + vj[q].z*vj[q].z + vj[q].w*vj[q].w;
        ssk += vk[q].x*vk[q].x + vk[q].y*vk[q].y + vk[q].z*vk[q].z + vk[q].w*vk[q].w;
        dij += vi[q].x*vj[q].x + vi[q].y*vj[q].y + vi[q].z*vj[q].z + vi[q].w*vj[q].w;
    }
    #pragma unroll
    for (int off = 1; off <= 8; off <<= 1) {    // reduce over the 16 c-lanes
        ssi += __shfl_xor(ssi, off);
        ssj += __shfl_xor(ssj, off);
        ssk += __shfl_xor(ssk, off);
        dij += __shfl_xor(dij, off);
    }
    const float rn = 1.0f / fmaxf(sqrtf(ssi), 1e-12f);
    const float ri = rn * LOG2E;                          // fold log2(e)
    const float rj = 1.0f / fmaxf(sqrtf(ssj), 1e-12f);
    const float rk = 1.0f / fmaxf(sqrtf(ssk), 1e-12f);

    uint4 uiv, ukv;
    {
        unsigned int wi[4], wk[4];
        #pragma unroll
        for (int q = 0; q < 4; ++q) {
            const float* fi = &vi[q].x;
            const float* fk = &vk[q].x;
            int a = 0, b = 0;
            a = __builtin_amdgcn_cvt_pk_fp8_f32(fi[0] * ri, fi[1] * ri, a, false);
            a = __builtin_amdgcn_cvt_pk_fp8_f32(fi[2] * ri, fi[3] * ri, a, true);
            b = __builtin_amdgcn_cvt_pk_fp8_f32(fk[0] * rk, fk[1] * rk, b, false);
            b = __builtin_amdgcn_cvt_pk_fp8_f32(fk[2] * rk, fk[3] * rk, b, true);
            wi[q] = (unsigned int)a;
            wk[q] = (unsigned int)b;
        }
        uiv = make_uint4(wi[0], wi[1], wi[2], wi[3]);
        ukv = make_uint4(wk[0], wk[1], wk[2], wk[3]);
    }
    const int f    = (row >> 5) * 4 + (c >> 2);
    const int lane = (row & 31) + 32 * ((c >> 1) & 1);
    const size_t off = (size_t)f * 2048 + (c & 1) * 1024 + lane * 16;
    *(uint4*)(zip + off) = uiv;
    *(uint4*)(zkp + off) = ukv;

    if (c == 0) {
        pos_logit[row] = dij * rn * rj * INV_T;   // plain 2*(zi.zj), no log2e
        rowsum[row]    = 0.0f;
    }
}

// ---------------------------------------------------------------------------
// Kernel 2: rows [by*128,+128) x cols [bx*512,+512) of exp2-sum of
// 2*log2e*(z_i . z_k). 4 waves = row slices (wave w: rows [w*32,+32)).
// Wave tile 32x32, 1 MFMA_scale_32x32x64 per step; 64 steps (nt 0..15,
// kt 0..3) fully unrolled. A: LDS frag (w*4+kt); B: Bbase + s*2048 (all
// waves same address -> L1 broadcast), register ring depth 4.
// ---------------------------------------------------------------------------
__global__ __launch_bounds__(256) void sim_mfma_kernel(
    const unsigned char* __restrict__ zip, const unsigned char* __restrict__ zkp,
    float* __restrict__ rowsum)
{
    __shared__ __attribute__((aligned(16))) unsigned char Alds[16 * 2048];

    const int t  = (int)threadIdx.x;
    const int w  = t >> 6;        // wave 0..3 = row slice
    const int l  = t & 63;
    const int rowBase = (int)blockIdx.y * BM;

    // ---- stage A panel: global frags [by*16,+16) contiguous 32 KB.
    const unsigned char* Ap = zip + (size_t)blockIdx.y * 16 * 2048;
    #pragma unroll
    for (int f = 0; f < 4; ++f) {
        const int fi = w * 4 + f;
        gload_lds16(Ap + (size_t)fi * 2048 +        (size_t)l * 16,
                    &Alds[fi * 2048]);
        gload_lds16(Ap + (size_t)fi * 2048 + 1024 + (size_t)l * 16,
                    &Alds[fi * 2048 + 1024]);
    }
    asm volatile("s_waitcnt vmcnt(0)" ::: "memory");
    __builtin_amdgcn_s_barrier();      // the ONLY barrier

    // ---- A frag read (LDS, split-half): frag w*4+kt; 16 B/lane per half.
    #define LDA(dst, kt_) {                                                   \
        const int fb_ = ((w * 4) + (kt_)) * 2048 + l * 16;                    \
        i32x4 lo_ = *(const i32x4*)&Alds[fb_];                                \
        i32x4 hi_ = *(const i32x4*)&Alds[fb_ + 1024];                         \
        dst = (i32x8){lo_[0], lo_[1], lo_[2], lo_[3],                         \
                      hi_[0], hi_[1], hi_[2], hi_[3]};                        \
    }
    // ---- B frag (global, split-half): frag s (= nt*4+kt) at Bbase+s*2048.
    const unsigned char* Bbase =
        zkp + ((size_t)(int)blockIdx.x * 16 * 4) * 2048 + (size_t)l * 16;
    #define LDB(dst, s_) {                                                    \
        const size_t fb_ = (size_t)(s_) * 2048;                               \
        i32x4 lo_ = *(const i32x4*)(Bbase + fb_);                             \
        i32x4 hi_ = *(const i32x4*)(Bbase + fb_ + 1024);                      \
        dst = (i32x8){lo_[0], lo_[1], lo_[2], lo_[3],                         \
                      hi_[0], hi_[1], hi_[2], hi_[3]};                        \
    }

    // ---- B ring, depth 4 (static names; slot = s & 3) ----
    i32x8 b0, b1, b2, b3;
    LDB(b0, 0); LDB(b1, 1); LDB(b2, 2); LDB(b3, 3);

    float partAcc[16] = {};

    #pragma unroll
    for (int nt = 0; nt < NT; ++nt) {
        f32x16 acc = {};

        #pragma unroll
        for (int k4 = 0; k4 < 4; ++k4) {
            const int s  = nt * 4 + k4;           // compile-time
            const int s4 = (s + 4 > NT * 4 - 1) ? (NT * 4 - 1) : (s + 4);

            i32x8 a;
            LDA(a, k4);

            __builtin_amdgcn_s_setprio(1);
            acc = __builtin_amdgcn_mfma_scale_f32_32x32x64_f8f6f4(
                a,
                (s % 4 == 0) ? b0 : (s % 4 == 1) ? b1
                             : (s % 4 == 2) ? b2 : b3,
                acc,
                0, 0,                 // cbsz=fp8(A), blgp=fp8(B)
                0, 0x00000080,        // scale A = 2.0 (1/T)
                0, 0x0000007F);       // scale B = 1.0
            __builtin_amdgcn_s_setprio(0);

            // refill this slot for step s+4 (distance 4)
            if (s % 4 == 0)      { LDB(b0, s4); }
            else if (s % 4 == 1) { LDB(b1, s4); }
            else if (s % 4 == 2) { LDB(b2, s4); }
            else                 { LDB(b3, s4); }
        }

        // per-tile epilogue: bare exp2 + in-lane partial sums
        #pragma unroll
        for (int r = 0; r < 16; ++r)
            partAcc[r] += exp2f(acc[r]);
    }
    #undef LDA
    #undef LDB

    // wave epilogue: reduce across the 32 column-lanes (xor<32 stays in half)
    #pragma unroll
    for (int off = 1; off <= 16; off <<= 1)
        #pragma unroll
        for (int r = 0; r < 16; ++r)
            partAcc[r] += __shfl_xor(partAcc[r], off);

    if ((l & 31) == 0) {
        const int hi = l >> 5;           // C/D: row = (r&3) + 8*(r>>2) + 4*hi
        #pragma unroll
        for (int r = 0; r < 16; ++r) {
            const int rr = (r & 3) + 8 * (r >> 2) + 4 * hi;
            atomicAdd(&rowsum[rowBase + w * 32 + rr], partAcc[r]);
        }
    }
}

// ---------------------------------------------------------------------------
// Kernel 3: loss = mean_b [ log(exp(pos_b) + rowsum_b) - pos_b ]
// ---------------------------------------------------------------------------
__global__ __launch_bounds__(1024) void finalize_kernel(
    const float* __restrict__ pos_logit, const float* __restrict__ rowsum,
    float* __restrict__ out, int B)
{
    __shared__ float red[1024];
    float acc = 0.f;
    for (int b = (int)threadIdx.x; b < B; b += 1024) {
        const float pl = pos_logit[b];
        acc += logf(expf(pl) + rowsum[b]) - pl;
    }
    red[threadIdx.x] = acc;
    __syncthreads();
    #pragma unroll
    for (int s = 512; s; s >>= 1) {
        if ((int)threadIdx.x < s) red[threadIdx.x] += red[threadIdx.x + s];
        __syncthreads();
    }
    if (threadIdx.x == 0) out[0] = red[0] / (float)B;
}

// ---------------------------------------------------------------------------
extern "C" void kernel_launch(void* const* d_in, const int* in_sizes, int n_in,
                              void* d_out, int out_size, void* d_ws, size_t ws_size,
                              hipStream_t stream)
{
    const float* ei = (const float*)d_in[0];
    const float* ej = (const float*)d_in[1];
    const float* ek = (const float*)d_in[2];
    const int B = in_sizes[0] / D_DIM;   // 8192

    unsigned char* zip = (unsigned char*)d_ws;              // 2 MB packed fp8
    unsigned char* zkp = zip + (size_t)B * D_DIM;           // 2 MB packed fp8
    float* rowsum      = (float*)(zkp + (size_t)B * D_DIM);
    float* pos_logit   = rowsum + B;

    prep_kernel<<<dim3(B / 16), dim3(256), 0, stream>>>(
        ei, ej, ek, zip, zkp, pos_logit, rowsum);

    dim3 grid(B / (NT * 32), B / BM);    // (16, 64) = 1024 blocks
    sim_mfma_kernel<<<grid, dim3(256), 0, stream>>>(zip, zkp, rowsum);

    finalize_kernel<<<dim3(1), dim3(1024), 0, stream>>>(
        pos_logit, rowsum, (float*)d_out, B);
}

// Round 20
// 45.887 us; speedup vs baseline: 1.2345x; 1.0287x over previous
//
#include <hip/hip_runtime.h>
#include <cstdint>
#include <cstddef>

// ContrastiveLoss: B=8192, D=256 fp32 inputs.
// loss = mean_b [ log( exp(2*pos_b) + sum_c exp(2*z_i[b].z_k[c]) ) - 2*pos_b ]
// R19: R18 (32x32 wave tile, <=128-reg occupancy bin, 16 waves/CU) with the
// last dependent-load leak removed: A's 4 fragments are hoisted to REGISTERS
// once per wave (32 VGPR) — no LDS, no barrier, loop = 1 MFMA + distance-4
// B-ring refill. All 4 waves/block read the same B address (L1 broadcast).
// z_i packed with log2(e) folded; scale A = 2.0 (0x80) = the 1/T.
// exp2 fused per col-tile; lane-reduce + atomics once per wave at the end.

constexpr int   D_DIM = 256;
constexpr float INV_T = 2.0f;        // 1/T, T=0.5
constexpr float LOG2E = 1.44269504f;

constexpr int BM = 128;         // block rows
constexpr int NT = 16;          // col-tiles per block (each 32 cols)

typedef __attribute__((ext_vector_type(8)))  int   i32x8;
typedef __attribute__((ext_vector_type(4)))  int   i32x4;
typedef __attribute__((ext_vector_type(16))) float f32x16;

// ---------------------------------------------------------------------------
// Kernel 1: per-16-row group: norms, pos_logit, rowsum init, PACKED e4m3 out.
// (unchanged from R17/R18 — verified correct)
// Split-half pack: frag f = (row>>5)*4 + (c>>2);
//   lane = (row&31) + 32*((c>>1)&1); half = c&1;
//   byte = f*2048 + half*1024 + lane*16.
// z_i additionally scaled by LOG2E (so GEMM's scale-A=2.0 yields exp2 arg).
// ---------------------------------------------------------------------------
__global__ __launch_bounds__(256) void prep_kernel(
    const float* __restrict__ ei, const float* __restrict__ ej,
    const float* __restrict__ ek,
    unsigned char* __restrict__ zip, unsigned char* __restrict__ zkp,
    float* __restrict__ pos_logit, float* __restrict__ rowsum)
{
    const int t  = (int)threadIdx.x;
    const int rl = t >> 4;              // row within group (0..15)
    const int c  = t & 15;              // 16-elem chunk (0..15)
    const int g  = (int)blockIdx.x;     // 16-row group
    const int row = g * 16 + rl;

    const float4* pi = (const float4*)(ei + (size_t)row * D_DIM + c * 16);
    const float4* pj = (const float4*)(ej + (size_t)row * D_DIM + c * 16);
    const float4* pk = (const float4*)(ek + (size_t)row * D_DIM + c * 16);
    float4 vi[4], vj[4], vk[4];
    #pragma unroll
    for (int q = 0; q < 4; ++q) { vi[q] = pi[q]; vj[q] = pj[q]; vk[q] = pk[q]; }

    float ssi = 0.f, ssj = 0.f, ssk = 0.f, dij = 0.f;
    #pragma unroll
    for (int q = 0; q < 4; ++q) {
        ssi += vi[q].x*vi[q].x + vi[q].y*vi[q].y + vi[q].z*vi[q].z + vi[q].w*vi[q].w;
        ssj += vj[q].x*vj[q].x + vj[q].y*vj[q].y + vj[q].z*vj[q].z + vj[q].w*vj[q].w;
        ssk += vk[q].x*vk[q].x + vk[q].y*vk[q].y + vk[q].z*vk[q].z + vk[q].w*vk[q].w;
        dij += vi[q].x*vj[q].x + vi[q].y*vj[q].y + vi[q].z*vj[q].z + vi[q].w*vj[q].w;
    }
    #pragma unroll
    for (int off = 1; off <= 8; off <<= 1) {    // reduce over the 16 c-lanes
        ssi += __shfl_xor(ssi, off);
        ssj += __shfl_xor(ssj, off);
        ssk += __shfl_xor(ssk, off);
        dij += __shfl_xor(dij, off);
    }
    const float rn = 1.0f / fmaxf(sqrtf(ssi), 1e-12f);
    const float ri = rn * LOG2E;                          // fold log2(e)
    const float rj = 1.0f / fmaxf(sqrtf(ssj), 1e-12f);
    const float rk = 1.0f / fmaxf(sqrtf(ssk), 1e-12f);

    uint4 uiv, ukv;
    {
        unsigned int wi[4], wk[4];
        #pragma unroll
        for (int q = 0; q < 4; ++q) {
            const float* fi = &vi[q].x;
            const float* fk = &vk[q].x;
            int a = 0, b = 0;
            a = __builtin_amdgcn_cvt_pk_fp8_f32(fi[0] * ri, fi[1] * ri, a, false);
            a = __builtin_amdgcn_cvt_pk_fp8_f32(fi[2] * ri, fi[3] * ri, a, true);
            b = __builtin_amdgcn_cvt_pk_fp8_f32(fk[0] * rk, fk[1] * rk, b, false);
            b = __builtin_amdgcn_cvt_pk_fp8_f32(fk[2] * rk, fk[3] * rk, b, true);
            wi[q] = (unsigned int)a;
            wk[q] = (unsigned int)b;
        }
        uiv = make_uint4(wi[0], wi[1], wi[2], wi[3]);
        ukv = make_uint4(wk[0], wk[1], wk[2], wk[3]);
    }
    const int f    = (row >> 5) * 4 + (c >> 2);
    const int lane = (row & 31) + 32 * ((c >> 1) & 1);
    const size_t off = (size_t)f * 2048 + (c & 1) * 1024 + lane * 16;
    *(uint4*)(zip + off) = uiv;
    *(uint4*)(zkp + off) = ukv;

    if (c == 0) {
        pos_logit[row] = dij * rn * rj * INV_T;   // plain 2*(zi.zj), no log2e
        rowsum[row]    = 0.0f;
    }
}

// ---------------------------------------------------------------------------
// Kernel 2: rows [by*128,+128) x cols [bx*512,+512) of exp2-sum of
// 2*log2e*(z_i . z_k). 4 waves = row slices (wave w: rows [w*32,+32)).
// Wave tile 32x32, 1 MFMA_scale_32x32x64 per step; 64 steps (nt 0..15,
// kt 0..3) fully unrolled. A: 4 frags in REGISTERS (a0..a3, loaded once,
// 32 VGPR). B: Bbase + s*2048 (same addr across waves -> L1 broadcast),
// register ring depth 4. No LDS, no barriers.
// ---------------------------------------------------------------------------
__global__ __launch_bounds__(256) void sim_mfma_kernel(
    const unsigned char* __restrict__ zip, const unsigned char* __restrict__ zkp,
    float* __restrict__ rowsum)
{
    const int t  = (int)threadIdx.x;
    const int w  = t >> 6;        // wave 0..3 = row slice
    const int l  = t & 63;
    const int rowBase = (int)blockIdx.y * BM;

    // ---- A frags -> registers (once): global frag (by*4+w)*4 + kt.
    const unsigned char* Abase =
        zip + ((size_t)((int)blockIdx.y * 4 + w) * 4) * 2048 + (size_t)l * 16;
    #define LDFRAG(dst, base, fb_) {                                          \
        i32x4 lo_ = *(const i32x4*)((base) + (fb_));                          \
        i32x4 hi_ = *(const i32x4*)((base) + (fb_) + 1024);                   \
        dst = (i32x8){lo_[0], lo_[1], lo_[2], lo_[3],                         \
                      hi_[0], hi_[1], hi_[2], hi_[3]};                        \
    }
    i32x8 a0, a1, a2, a3;
    LDFRAG(a0, Abase, 0);
    LDFRAG(a1, Abase, 2048);
    LDFRAG(a2, Abase, 4096);
    LDFRAG(a3, Abase, 6144);

    // ---- B frag (global, split-half): frag s (= nt*4+kt) at Bbase+s*2048.
    const unsigned char* Bbase =
        zkp + ((size_t)(int)blockIdx.x * 16 * 4) * 2048 + (size_t)l * 16;

    // ---- B ring, depth 4 (static names; slot = s & 3) ----
    i32x8 b0, b1, b2, b3;
    LDFRAG(b0, Bbase, 0);
    LDFRAG(b1, Bbase, 2048);
    LDFRAG(b2, Bbase, 4096);
    LDFRAG(b3, Bbase, 6144);

    float partAcc[16] = {};

    #pragma unroll
    for (int nt = 0; nt < NT; ++nt) {
        f32x16 acc = {};

        #pragma unroll
        for (int k4 = 0; k4 < 4; ++k4) {
            const int s  = nt * 4 + k4;           // compile-time
            const int s4 = (s + 4 > NT * 4 - 1) ? (NT * 4 - 1) : (s + 4);

            __builtin_amdgcn_s_setprio(1);
            acc = __builtin_amdgcn_mfma_scale_f32_32x32x64_f8f6f4(
                (k4 == 0) ? a0 : (k4 == 1) ? a1 : (k4 == 2) ? a2 : a3,
                (s % 4 == 0) ? b0 : (s % 4 == 1) ? b1
                             : (s % 4 == 2) ? b2 : b3,
                acc,
                0, 0,                 // cbsz=fp8(A), blgp=fp8(B)
                0, 0x00000080,        // scale A = 2.0 (1/T)
                0, 0x0000007F);       // scale B = 1.0
            __builtin_amdgcn_s_setprio(0);

            // refill this slot for step s+4 (distance 4)
            if (s % 4 == 0)      { LDFRAG(b0, Bbase, (size_t)s4 * 2048); }
            else if (s % 4 == 1) { LDFRAG(b1, Bbase, (size_t)s4 * 2048); }
            else if (s % 4 == 2) { LDFRAG(b2, Bbase, (size_t)s4 * 2048); }
            else                 { LDFRAG(b3, Bbase, (size_t)s4 * 2048); }
        }

        // per-tile epilogue: bare exp2 + in-lane partial sums
        #pragma unroll
        for (int r = 0; r < 16; ++r)
            partAcc[r] += exp2f(acc[r]);
    }
    #undef LDFRAG

    // wave epilogue: reduce across the 32 column-lanes (xor<32 stays in half)
    #pragma unroll
    for (int off = 1; off <= 16; off <<= 1)
        #pragma unroll
        for (int r = 0; r < 16; ++r)
            partAcc[r] += __shfl_xor(partAcc[r], off);

    if ((l & 31) == 0) {
        const int hi = l >> 5;           // C/D: row = (r&3) + 8*(r>>2) + 4*hi
        #pragma unroll
        for (int r = 0; r < 16; ++r) {
            const int rr = (r & 3) + 8 * (r >> 2) + 4 * hi;
            atomicAdd(&rowsum[rowBase + w * 32 + rr], partAcc[r]);
        }
    }
}

// ---------------------------------------------------------------------------
// Kernel 3: loss = mean_b [ log(exp(pos_b) + rowsum_b) - pos_b ]
// ---------------------------------------------------------------------------
__global__ __launch_bounds__(1024) void finalize_kernel(
    const float* __restrict__ pos_logit, const float* __restrict__ rowsum,
    float* __restrict__ out, int B)
{
    __shared__ float red[1024];
    float acc = 0.f;
    for (int b = (int)threadIdx.x; b < B; b += 1024) {
        const float pl = pos_logit[b];
        acc += logf(expf(pl) + rowsum[b]) - pl;
    }
    red[threadIdx.x] = acc;
    __syncthreads();
    #pragma unroll
    for (int s = 512; s; s >>= 1) {
        if ((int)threadIdx.x < s) red[threadIdx.x] += red[threadIdx.x + s];
        __syncthreads();
    }
    if (threadIdx.x == 0) out[0] = red[0] / (float)B;
}

// ---------------------------------------------------------------------------
extern "C" void kernel_launch(void* const* d_in, const int* in_sizes, int n_in,
                              void* d_out, int out_size, void* d_ws, size_t ws_size,
                              hipStream_t stream)
{
    const float* ei = (const float*)d_in[0];
    const float* ej = (const float*)d_in[1];
    const float* ek = (const float*)d_in[2];
    const int B = in_sizes[0] / D_DIM;   // 8192

    unsigned char* zip = (unsigned char*)d_ws;              // 2 MB packed fp8
    unsigned char* zkp = zip + (size_t)B * D_DIM;           // 2 MB packed fp8
    float* rowsum      = (float*)(zkp + (size_t)B * D_DIM);
    float* pos_logit   = rowsum + B;

    prep_kernel<<<dim3(B / 16), dim3(256), 0, stream>>>(
        ei, ej, ek, zip, zkp, pos_logit, rowsum);

    dim3 grid(B / (NT * 32), B / BM);    // (16, 64) = 1024 blocks
    sim_mfma_kernel<<<grid, dim3(256), 0, stream>>>(zip, zkp, rowsum);

    finalize_kernel<<<dim3(1), dim3(1024), 0, stream>>>(
        pos_logit, rowsum, (float*)d_out, B);
}

// Round 21
// 41.495 us; speedup vs baseline: 1.3652x; 1.1058x over previous
//
#include <hip/hip_runtime.h>
#include <cstdint>
#include <cstddef>

// ContrastiveLoss: B=8192, D=256 fp32 inputs.
// loss = mean_b [ log( exp(2*pos_b) + sum_c exp(2*z_i[b].z_k[c]) ) - 2*pos_b ]
// R20: R19 + grid transpose for B-panel locality: blockIdx.x = ROW block
// (fast dim), blockIdx.y = COL block -> co-resident blocks on a CU share the
// same B panel (same load addresses -> L1 hits), 4x less unique B traffic.
// Everything else identical to R19 (verified): 32x32 wave tile, A in regs
// (32 VGPR), B register ring depth 4, no LDS, no barriers, exp2 epilogue.

constexpr int   D_DIM = 256;
constexpr float INV_T = 2.0f;        // 1/T, T=0.5
constexpr float LOG2E = 1.44269504f;

constexpr int BM = 128;         // block rows
constexpr int NT = 16;          // col-tiles per block (each 32 cols)

typedef __attribute__((ext_vector_type(8)))  int   i32x8;
typedef __attribute__((ext_vector_type(4)))  int   i32x4;
typedef __attribute__((ext_vector_type(16))) float f32x16;

// ---------------------------------------------------------------------------
// Kernel 1: per-16-row group: norms, pos_logit, rowsum init, PACKED e4m3 out.
// (unchanged from R17/R18/R19 — verified correct)
// Split-half pack: frag f = (row>>5)*4 + (c>>2);
//   lane = (row&31) + 32*((c>>1)&1); half = c&1;
//   byte = f*2048 + half*1024 + lane*16.
// z_i additionally scaled by LOG2E (so GEMM's scale-A=2.0 yields exp2 arg).
// ---------------------------------------------------------------------------
__global__ __launch_bounds__(256) void prep_kernel(
    const float* __restrict__ ei, const float* __restrict__ ej,
    const float* __restrict__ ek,
    unsigned char* __restrict__ zip, unsigned char* __restrict__ zkp,
    float* __restrict__ pos_logit, float* __restrict__ rowsum)
{
    const int t  = (int)threadIdx.x;
    const int rl = t >> 4;              // row within group (0..15)
    const int c  = t & 15;              // 16-elem chunk (0..15)
    const int g  = (int)blockIdx.x;     // 16-row group
    const int row = g * 16 + rl;

    const float4* pi = (const float4*)(ei + (size_t)row * D_DIM + c * 16);
    const float4* pj = (const float4*)(ej + (size_t)row * D_DIM + c * 16);
    const float4* pk = (const float4*)(ek + (size_t)row * D_DIM + c * 16);
    float4 vi[4], vj[4], vk[4];
    #pragma unroll
    for (int q = 0; q < 4; ++q) { vi[q] = pi[q]; vj[q] = pj[q]; vk[q] = pk[q]; }

    float ssi = 0.f, ssj = 0.f, ssk = 0.f, dij = 0.f;
    #pragma unroll
    for (int q = 0; q < 4; ++q) {
        ssi += vi[q].x*vi[q].x + vi[q].y*vi[q].y + vi[q].z*vi[q].z + vi[q].w*vi[q].w;
        ssj += vj[q].x*vj[q].x + vj[q].y*vj[q].y + vj[q].z*vj[q].z + vj[q].w*vj[q].w;
        ssk += vk[q].x*vk[q].x + vk[q].y*vk[q].y + vk[q].z*vk[q].z + vk[q].w*vk[q].w;
        dij += vi[q].x*vj[q].x + vi[q].y*vj[q].y + vi[q].z*vj[q].z + vi[q].w*vj[q].w;
    }
    #pragma unroll
    for (int off = 1; off <= 8; off <<= 1) {    // reduce over the 16 c-lanes
        ssi += __shfl_xor(ssi, off);
        ssj += __shfl_xor(ssj, off);
        ssk += __shfl_xor(ssk, off);
        dij += __shfl_xor(dij, off);
    }
    const float rn = 1.0f / fmaxf(sqrtf(ssi), 1e-12f);
    const float ri = rn * LOG2E;                          // fold log2(e)
    const float rj = 1.0f / fmaxf(sqrtf(ssj), 1e-12f);
    const float rk = 1.0f / fmaxf(sqrtf(ssk), 1e-12f);

    uint4 uiv, ukv;
    {
        unsigned int wi[4], wk[4];
        #pragma unroll
        for (int q = 0; q < 4; ++q) {
            const float* fi = &vi[q].x;
            const float* fk = &vk[q].x;
            int a = 0, b = 0;
            a = __builtin_amdgcn_cvt_pk_fp8_f32(fi[0] * ri, fi[1] * ri, a, false);
            a = __builtin_amdgcn_cvt_pk_fp8_f32(fi[2] * ri, fi[3] * ri, a, true);
            b = __builtin_amdgcn_cvt_pk_fp8_f32(fk[0] * rk, fk[1] * rk, b, false);
            b = __builtin_amdgcn_cvt_pk_fp8_f32(fk[2] * rk, fk[3] * rk, b, true);
            wi[q] = (unsigned int)a;
            wk[q] = (unsigned int)b;
        }
        uiv = make_uint4(wi[0], wi[1], wi[2], wi[3]);
        ukv = make_uint4(wk[0], wk[1], wk[2], wk[3]);
    }
    const int f    = (row >> 5) * 4 + (c >> 2);
    const int lane = (row & 31) + 32 * ((c >> 1) & 1);
    const size_t off = (size_t)f * 2048 + (c & 1) * 1024 + lane * 16;
    *(uint4*)(zip + off) = uiv;
    *(uint4*)(zkp + off) = ukv;

    if (c == 0) {
        pos_logit[row] = dij * rn * rj * INV_T;   // plain 2*(zi.zj), no log2e
        rowsum[row]    = 0.0f;
    }
}

// ---------------------------------------------------------------------------
// Kernel 2: rows [bR*128,+128) x cols [bC*512,+512) of exp2-sum of
// 2*log2e*(z_i . z_k), where bR = blockIdx.x (FAST dim -> co-resident
// blocks share bC's B panel), bC = blockIdx.y.
// 4 waves = row slices; wave tile 32x32; 64 steps fully unrolled.
// A: 4 frags in registers (loaded once). B: ring depth 4, same address
// across all co-resident waves -> L1 broadcast. No LDS, no barriers.
// ---------------------------------------------------------------------------
__global__ __launch_bounds__(256) void sim_mfma_kernel(
    const unsigned char* __restrict__ zip, const unsigned char* __restrict__ zkp,
    float* __restrict__ rowsum)
{
    const int t  = (int)threadIdx.x;
    const int w  = t >> 6;        // wave 0..3 = row slice
    const int l  = t & 63;
    const int bR = (int)blockIdx.x;    // row block (fast)
    const int bC = (int)blockIdx.y;    // col block
    const int rowBase = bR * BM;

    // ---- A frags -> registers (once): global frag (bR*4+w)*4 + kt.
    const unsigned char* Abase =
        zip + ((size_t)(bR * 4 + w) * 4) * 2048 + (size_t)l * 16;
    #define LDFRAG(dst, base, fb_) {                                          \
        i32x4 lo_ = *(const i32x4*)((base) + (fb_));                          \
        i32x4 hi_ = *(const i32x4*)((base) + (fb_) + 1024);                   \
        dst = (i32x8){lo_[0], lo_[1], lo_[2], lo_[3],                         \
                      hi_[0], hi_[1], hi_[2], hi_[3]};                        \
    }
    i32x8 a0, a1, a2, a3;
    LDFRAG(a0, Abase, 0);
    LDFRAG(a1, Abase, 2048);
    LDFRAG(a2, Abase, 4096);
    LDFRAG(a3, Abase, 6144);

    // ---- B frag (global, split-half): frag s (= nt*4+kt) at Bbase+s*2048.
    const unsigned char* Bbase =
        zkp + ((size_t)bC * 16 * 4) * 2048 + (size_t)l * 16;

    // ---- B ring, depth 4 (static names; slot = s & 3) ----
    i32x8 b0, b1, b2, b3;
    LDFRAG(b0, Bbase, 0);
    LDFRAG(b1, Bbase, 2048);
    LDFRAG(b2, Bbase, 4096);
    LDFRAG(b3, Bbase, 6144);

    float partAcc[16] = {};

    #pragma unroll
    for (int nt = 0; nt < NT; ++nt) {
        f32x16 acc = {};

        #pragma unroll
        for (int k4 = 0; k4 < 4; ++k4) {
            const int s  = nt * 4 + k4;           // compile-time
            const int s4 = (s + 4 > NT * 4 - 1) ? (NT * 4 - 1) : (s + 4);

            __builtin_amdgcn_s_setprio(1);
            acc = __builtin_amdgcn_mfma_scale_f32_32x32x64_f8f6f4(
                (k4 == 0) ? a0 : (k4 == 1) ? a1 : (k4 == 2) ? a2 : a3,
                (s % 4 == 0) ? b0 : (s % 4 == 1) ? b1
                             : (s % 4 == 2) ? b2 : b3,
                acc,
                0, 0,                 // cbsz=fp8(A), blgp=fp8(B)
                0, 0x00000080,        // scale A = 2.0 (1/T)
                0, 0x0000007F);       // scale B = 1.0
            __builtin_amdgcn_s_setprio(0);

            // refill this slot for step s+4 (distance 4)
            if (s % 4 == 0)      { LDFRAG(b0, Bbase, (size_t)s4 * 2048); }
            else if (s % 4 == 1) { LDFRAG(b1, Bbase, (size_t)s4 * 2048); }
            else if (s % 4 == 2) { LDFRAG(b2, Bbase, (size_t)s4 * 2048); }
            else                 { LDFRAG(b3, Bbase, (size_t)s4 * 2048); }
        }

        // per-tile epilogue: bare exp2 + in-lane partial sums
        #pragma unroll
        for (int r = 0; r < 16; ++r)
            partAcc[r] += exp2f(acc[r]);
    }
    #undef LDFRAG

    // wave epilogue: reduce across the 32 column-lanes (xor<32 stays in half)
    #pragma unroll
    for (int off = 1; off <= 16; off <<= 1)
        #pragma unroll
        for (int r = 0; r < 16; ++r)
            partAcc[r] += __shfl_xor(partAcc[r], off);

    if ((l & 31) == 0) {
        const int hi = l >> 5;           // C/D: row = (r&3) + 8*(r>>2) + 4*hi
        #pragma unroll
        for (int r = 0; r < 16; ++r) {
            const int rr = (r & 3) + 8 * (r >> 2) + 4 * hi;
            atomicAdd(&rowsum[rowBase + w * 32 + rr], partAcc[r]);
        }
    }
}

// ---------------------------------------------------------------------------
// Kernel 3: loss = mean_b [ log(exp(pos_b) + rowsum_b) - pos_b ]
// ---------------------------------------------------------------------------
__global__ __launch_bounds__(1024) void finalize_kernel(
    const float* __restrict__ pos_logit, const float* __restrict__ rowsum,
    float* __restrict__ out, int B)
{
    __shared__ float red[1024];
    float acc = 0.f;
    for (int b = (int)threadIdx.x; b < B; b += 1024) {
        const float pl = pos_logit[b];
        acc += logf(expf(pl) + rowsum[b]) - pl;
    }
    red[threadIdx.x] = acc;
    __syncthreads();
    #pragma unroll
    for (int s = 512; s; s >>= 1) {
        if ((int)threadIdx.x < s) red[threadIdx.x] += red[threadIdx.x + s];
        __syncthreads();
    }
    if (threadIdx.x == 0) out[0] = red[0] / (float)B;
}

// ---------------------------------------------------------------------------
extern "C" void kernel_launch(void* const* d_in, const int* in_sizes, int n_in,
                              void* d_out, int out_size, void* d_ws, size_t ws_size,
                              hipStream_t stream)
{
    const float* ei = (const float*)d_in[0];
    const float* ej = (const float*)d_in[1];
    const float* ek = (const float*)d_in[2];
    const int B = in_sizes[0] / D_DIM;   // 8192

    unsigned char* zip = (unsigned char*)d_ws;              // 2 MB packed fp8
    unsigned char* zkp = zip + (size_t)B * D_DIM;           // 2 MB packed fp8
    float* rowsum      = (float*)(zkp + (size_t)B * D_DIM);
    float* pos_logit   = rowsum + B;

    prep_kernel<<<dim3(B / 16), dim3(256), 0, stream>>>(
        ei, ej, ek, zip, zkp, pos_logit, rowsum);

    // grid: x = ROW blocks (fast -> co-resident blocks share the B panel),
    //       y = COL blocks
    dim3 grid(B / BM, B / (NT * 32));    // (64, 16) = 1024 blocks
    sim_mfma_kernel<<<grid, dim3(256), 0, stream>>>(zip, zkp, rowsum);

    finalize_kernel<<<dim3(1), dim3(1024), 0, stream>>>(
        pos_logit, rowsum, (float*)d_out, B);
}